// Round 11
// baseline (553.983 us; speedup 1.0000x reference)
//
#include <hip/hip_runtime.h>
#include <hip/hip_fp16.h>

// Sinkhorn OT: n=m=4096, d=32, reg=0.1, 100 iterations, uniform marginals.
// R16 = R15 (plain-launch persistent kernel, matrix in VGPRs, fused
// val|phase row mailboxes) with the per-half-pass critical path shortened:
//   - 256 blocks x 1024 thr, ONE WAVE PER ROW (16 rows/block). Each lane
//     holds its whole row: 8+8 uint4 = 64 VGPR (launch_bounds(1024,4) caps
//     at 128). Co-residency now unconditional: 4096 waves fit the device
//     whatever the placement.
//   - wave reduces its row and lane0 publishes IMMEDIATELY: no part[]
//     cross-wave combine, no second barrier.
//   - double-buffered operand LDS (v->buf0, u->buf1): ONE barrier per
//     half-pass is provably safe (a thread staging buffer X at half-pass
//     p+2 passed the barrier at p+1, which required all threads to finish
//     compute-from-X at p).
//   - staging poll is 4 mailboxes/thread (was 8).
// BIT-EXACT with R11..R15: chains c=0..3 replicate the old hlf=0 wave's
// uint4 sequence, c=4..7 the hlf=1 wave's; two shfl-reduce trees (s0,s1)
// replicate part[2q]/part[2q+1]; final A/(s0+s1) identical.
// Freeze (v(t)==v(t-2) bitwise, phase bit15) and the exact uniform break
// are unchanged. K-build and epilogue unchanged from R15.

#define NN 4096
#define MM 4096
#define DD 32
#define N_ITERS 100

static constexpr float INV_REG = 10.0f;
static constexpr float A_MARG  = 1.0f / 4096.0f;
static constexpr float B_MARG  = 1.0f / 4096.0f;

typedef _Float16 h2_t __attribute__((ext_vector_type(2)));

static __device__ __forceinline__ float dot2(unsigned a, unsigned b, float acc) {
#if __has_builtin(__builtin_amdgcn_fdot2)
    return __builtin_amdgcn_fdot2(__builtin_bit_cast(h2_t, a),
                                  __builtin_bit_cast(h2_t, b), acc, false);
#else
    float2 fa = __half22float2(*(const __half2*)&a);
    float2 fb = __half22float2(*(const __half2*)&b);
    acc = fmaf(fa.x, fb.x, acc);
    return fmaf(fa.y, fb.y, acc);
#endif
}

static __device__ __forceinline__ unsigned ld_dev_u32(const unsigned* p) {
    return __hip_atomic_load(p, __ATOMIC_RELAXED, __HIP_MEMORY_SCOPE_AGENT);
}
static __device__ __forceinline__ void st_dev_u32(unsigned* p, unsigned v) {
    __hip_atomic_store(p, v, __ATOMIC_RELAXED, __HIP_MEMORY_SCOPE_AGENT);
}

// ---------------------------------------------------------------------------
// One fused K-build dispatch. z=0: Kh[i][j]=exp(-||x_i-y_j||^2/reg) from
// (p=x, q=y); z=1: KTh from (p=y, q=x). z==0,by==0 also zeroes the row
// mailboxes (phase 0 = invalid).
// grid: (16, 256, 2), block 256
// ---------------------------------------------------------------------------
__global__ void compute_K_half(const float* __restrict__ x, const float* __restrict__ y,
                               __half* __restrict__ Kh, __half* __restrict__ KTh,
                               unsigned* __restrict__ mbu, unsigned* __restrict__ mbv) {
    const int tid = threadIdx.x;
    const int j   = blockIdx.x * 256 + tid;
    const int r0  = blockIdx.y * 16;
    const int z   = blockIdx.z;
    const float* __restrict__ p = z ? y : x;
    const float* __restrict__ q = z ? x : y;
    __half* __restrict__ dst    = z ? KTh : Kh;

    if (z == 0 && blockIdx.y == 0) {
        mbu[j] = 0u;
        mbv[j] = 0u;
    }

    float qv[DD];
    const float4* q4 = (const float4*)(q + (size_t)j * DD);
#pragma unroll
    for (int k = 0; k < DD / 4; ++k) {
        float4 t = q4[k];
        qv[4 * k + 0] = t.x; qv[4 * k + 1] = t.y;
        qv[4 * k + 2] = t.z; qv[4 * k + 3] = t.w;
    }

    __shared__ float ps[16 * DD];
    ps[tid]       = p[(size_t)r0 * DD + tid];
    ps[tid + 256] = p[(size_t)r0 * DD + tid + 256];
    __syncthreads();

#pragma unroll 4
    for (int ii = 0; ii < 16; ++ii) {
        float acc = 0.0f;
#pragma unroll
        for (int k = 0; k < DD; ++k) {
            float d = ps[ii * DD + k] - qv[k];
            acc = fmaf(d, d, acc);
        }
        dst[(size_t)(r0 + ii) * MM + j] = __float2half(__expf(-acc * INV_REG));
    }
}

// ---------------------------------------------------------------------------
// Persistent kernel: all 100 iterations. 256 blocks x 1024 thr; one wave
// per row; matrix register-resident; fused val|phase row mailboxes;
// double-buffered operand LDS; one barrier per half-pass.
// ---------------------------------------------------------------------------
__global__ void __launch_bounds__(1024, 4)
sinkhorn_persist(const __half* __restrict__ Kh, const __half* __restrict__ KTh,
                 float* __restrict__ u32g, float* __restrict__ v32g,
                 unsigned* __restrict__ mbu, unsigned* __restrict__ mbv) {
    __shared__ __align__(16) __half vbuf0[MM];   // u-half operands (v-vector)
    __shared__ __align__(16) __half vbuf1[MM];   // v-half operands (u-vector)
    __shared__ unsigned fb_lds[16];
    const int tid  = threadIdx.x;
    const int lane = tid & 63;
    const int w    = tid >> 6;          // wave 0..15 = row-in-block
    const int bid  = blockIdx.x;        // 0..255
    const int i    = bid * 16 + w;      // this wave's row
    const uint4* __restrict__ MU = (const uint4*)(Kh  + (size_t)i * MM);
    const uint4* __restrict__ MV = (const uint4*)(KTh + (size_t)i * MM);
    unsigned short* __restrict__ vl0 = (unsigned short*)vbuf0;
    unsigned short* __restrict__ vl1 = (unsigned short*)vbuf1;

    // ---- whole row -> registers, ONCE (16 uint4 = 64 VGPR/lane) ----
    uint4 ku[8], kv[8];
#pragma unroll
    for (int c = 0; c < 8; ++c) ku[c] = MU[lane + 64 * c];
#pragma unroll
    for (int c = 0; c < 8; ++c) kv[c] = MV[lane + 64 * c];

    // freeze history: this row's prev-prev fp16 bits, lane0 register.
    unsigned histv = 0x10000u;   // impossible 16-bit value

    // seed buf0 with v(0) = 1/4096 (consumed by t=0 u-half)
    {
        const unsigned long long dv =
            (unsigned long long)__half_as_ushort(__float2half(B_MARG)) *
            0x0001000100010001ULL;
        ((unsigned long long*)vbuf0)[tid] = dv;
    }

    for (int t = 0; t < N_ITERS; ++t) {
        // ===== u-half stage: v(t-1) rows {k*1024+tid} -> buf0 =====
        if (t != 0) {
            const unsigned want = (unsigned)(2 * t) & 0x7fffu;   // v(t-1)
            unsigned g[4];
#pragma unroll
            for (int k = 0; k < 4; ++k) g[k] = ld_dev_u32(mbv + (k << 10) + tid);
            for (;;) {
                unsigned bad = 0u;
#pragma unroll
                for (int k = 0; k < 4; ++k)
                    if ((g[k] & 0x7fffu) != want) bad |= 1u << k;
                if (!bad) break;
                __builtin_amdgcn_s_sleep(1);
#pragma unroll
                for (int k = 0; k < 4; ++k)
                    if (bad & (1u << k)) g[k] = ld_dev_u32(mbv + (k << 10) + tid);
            }
            unsigned fzb = 0x8000u;
#pragma unroll
            for (int k = 0; k < 4; ++k) {
                vl0[(k << 10) + tid] = (unsigned short)(g[k] >> 16);
                fzb &= g[k];
            }
            const bool allf = __all(fzb != 0u);
            if (lane == 0) fb_lds[w] = allf ? 1u : 0u;
        }
        __syncthreads();
        if (t != 0 && (t & 1) == 0) {
            // v(t-1)==v(t-3) bitwise everywhere -> remaining iterations
            // bit-identical; u32g/v32g already final. Exact skip.
            unsigned f = 1u;
#pragma unroll
            for (int q = 0; q < 16; ++q) f &= fb_lds[q];
            if (f) break;
        }

        // ===== u-half compute: u = a / (Kh . v); lane0 publishes =====
        {
            const uint4* V = (const uint4*)vbuf0;
            uint4 a0 = V[lane], a1 = V[lane + 64], a2 = V[lane + 128], a3 = V[lane + 192];
            uint4 a4 = V[lane + 256], a5 = V[lane + 320], a6 = V[lane + 384], a7 = V[lane + 448];
            float x0 = 0.f, x1 = 0.f, x2 = 0.f, x3 = 0.f;
            float x4 = 0.f, x5 = 0.f, x6 = 0.f, x7 = 0.f;
            x0 = dot2(ku[0].x, a0.x, x0); x0 = dot2(ku[0].y, a0.y, x0);
            x0 = dot2(ku[0].z, a0.z, x0); x0 = dot2(ku[0].w, a0.w, x0);
            x1 = dot2(ku[1].x, a1.x, x1); x1 = dot2(ku[1].y, a1.y, x1);
            x1 = dot2(ku[1].z, a1.z, x1); x1 = dot2(ku[1].w, a1.w, x1);
            x2 = dot2(ku[2].x, a2.x, x2); x2 = dot2(ku[2].y, a2.y, x2);
            x2 = dot2(ku[2].z, a2.z, x2); x2 = dot2(ku[2].w, a2.w, x2);
            x3 = dot2(ku[3].x, a3.x, x3); x3 = dot2(ku[3].y, a3.y, x3);
            x3 = dot2(ku[3].z, a3.z, x3); x3 = dot2(ku[3].w, a3.w, x3);
            x4 = dot2(ku[4].x, a4.x, x4); x4 = dot2(ku[4].y, a4.y, x4);
            x4 = dot2(ku[4].z, a4.z, x4); x4 = dot2(ku[4].w, a4.w, x4);
            x5 = dot2(ku[5].x, a5.x, x5); x5 = dot2(ku[5].y, a5.y, x5);
            x5 = dot2(ku[5].z, a5.z, x5); x5 = dot2(ku[5].w, a5.w, x5);
            x6 = dot2(ku[6].x, a6.x, x6); x6 = dot2(ku[6].y, a6.y, x6);
            x6 = dot2(ku[6].z, a6.z, x6); x6 = dot2(ku[6].w, a6.w, x6);
            x7 = dot2(ku[7].x, a7.x, x7); x7 = dot2(ku[7].y, a7.y, x7);
            x7 = dot2(ku[7].z, a7.z, x7); x7 = dot2(ku[7].w, a7.w, x7);
            float s0 = (x0 + x1) + (x2 + x3);    // == old hlf=0 partial
            float s1 = (x4 + x5) + (x6 + x7);    // == old hlf=1 partial
#pragma unroll
            for (int off = 32; off > 0; off >>= 1) {
                s0 += __shfl_down(s0, off, 64);
                s1 += __shfl_down(s1, off, 64);
            }
            if (lane == 0) {
                float r = A_MARG / (s0 + s1);    // == old part[2q]+part[2q+1]
                u32g[i] = r;
                const unsigned val = (unsigned)__half_as_ushort(__float2half(r));
                st_dev_u32(mbu + i, (val << 16) | ((unsigned)(2 * t + 1) & 0x7fffu));
            }
        }

        // ===== v-half stage: u(t) rows {k*1024+tid} -> buf1 =====
        {
            const unsigned want = (unsigned)(2 * t + 1) & 0x7fffu;   // u(t)
            unsigned g[4];
#pragma unroll
            for (int k = 0; k < 4; ++k) g[k] = ld_dev_u32(mbu + (k << 10) + tid);
            for (;;) {
                unsigned bad = 0u;
#pragma unroll
                for (int k = 0; k < 4; ++k)
                    if ((g[k] & 0x7fffu) != want) bad |= 1u << k;
                if (!bad) break;
                __builtin_amdgcn_s_sleep(1);
#pragma unroll
                for (int k = 0; k < 4; ++k)
                    if (bad & (1u << k)) g[k] = ld_dev_u32(mbu + (k << 10) + tid);
            }
#pragma unroll
            for (int k = 0; k < 4; ++k)
                vl1[(k << 10) + tid] = (unsigned short)(g[k] >> 16);
        }
        __syncthreads();

        // ===== v-half compute: v = b / (KTh . u); lane0 publishes =====
        {
            const uint4* V = (const uint4*)vbuf1;
            uint4 a0 = V[lane], a1 = V[lane + 64], a2 = V[lane + 128], a3 = V[lane + 192];
            uint4 a4 = V[lane + 256], a5 = V[lane + 320], a6 = V[lane + 384], a7 = V[lane + 448];
            float x0 = 0.f, x1 = 0.f, x2 = 0.f, x3 = 0.f;
            float x4 = 0.f, x5 = 0.f, x6 = 0.f, x7 = 0.f;
            x0 = dot2(kv[0].x, a0.x, x0); x0 = dot2(kv[0].y, a0.y, x0);
            x0 = dot2(kv[0].z, a0.z, x0); x0 = dot2(kv[0].w, a0.w, x0);
            x1 = dot2(kv[1].x, a1.x, x1); x1 = dot2(kv[1].y, a1.y, x1);
            x1 = dot2(kv[1].z, a1.z, x1); x1 = dot2(kv[1].w, a1.w, x1);
            x2 = dot2(kv[2].x, a2.x, x2); x2 = dot2(kv[2].y, a2.y, x2);
            x2 = dot2(kv[2].z, a2.z, x2); x2 = dot2(kv[2].w, a2.w, x2);
            x3 = dot2(kv[3].x, a3.x, x3); x3 = dot2(kv[3].y, a3.y, x3);
            x3 = dot2(kv[3].z, a3.z, x3); x3 = dot2(kv[3].w, a3.w, x3);
            x4 = dot2(kv[4].x, a4.x, x4); x4 = dot2(kv[4].y, a4.y, x4);
            x4 = dot2(kv[4].z, a4.z, x4); x4 = dot2(kv[4].w, a4.w, x4);
            x5 = dot2(kv[5].x, a5.x, x5); x5 = dot2(kv[5].y, a5.y, x5);
            x5 = dot2(kv[5].z, a5.z, x5); x5 = dot2(kv[5].w, a5.w, x5);
            x6 = dot2(kv[6].x, a6.x, x6); x6 = dot2(kv[6].y, a6.y, x6);
            x6 = dot2(kv[6].z, a6.z, x6); x6 = dot2(kv[6].w, a6.w, x6);
            x7 = dot2(kv[7].x, a7.x, x7); x7 = dot2(kv[7].y, a7.y, x7);
            x7 = dot2(kv[7].z, a7.z, x7); x7 = dot2(kv[7].w, a7.w, x7);
            float s0 = (x0 + x1) + (x2 + x3);
            float s1 = (x4 + x5) + (x6 + x7);
#pragma unroll
            for (int off = 32; off > 0; off >>= 1) {
                s0 += __shfl_down(s0, off, 64);
                s1 += __shfl_down(s1, off, 64);
            }
            if (lane == 0) {
                float r = B_MARG / (s0 + s1);
                v32g[i] = r;
                const unsigned val = (unsigned)__half_as_ushort(__float2half(r));
                unsigned ph = (unsigned)(2 * t + 2) & 0x7fffu;
                if (t & 1) {   // v(t) vs v(t-2), register-resident history
                    if (val == histv) ph |= 0x8000u;
                    histv = val;
                }
                st_dev_u32(mbv + i, (val << 16) | ph);
            }
        }
        // no barrier here: buf0 overwrite at t+1 is fenced by the u-stage
        // barrier of t+1 (every thread reaches it only after its v-compute).
    }
}

// ---------------------------------------------------------------------------
// gamma[i][j] = u[i] * exp(-||x_i-y_j||^2/reg) * v[j]   (exact fp32 K)
// grid: (16, 256), block 256
// ---------------------------------------------------------------------------
__global__ void epilogue(const float* __restrict__ x, const float* __restrict__ y,
                         const float* __restrict__ u, const float* __restrict__ v,
                         float* __restrict__ out) {
    const int tid = threadIdx.x;
    const int j   = blockIdx.x * 256 + tid;
    const int r0  = blockIdx.y * 16;

    float yv[DD];
    const float4* y4 = (const float4*)(y + (size_t)j * DD);
#pragma unroll
    for (int k = 0; k < DD / 4; ++k) {
        float4 t = y4[k];
        yv[4 * k + 0] = t.x; yv[4 * k + 1] = t.y;
        yv[4 * k + 2] = t.z; yv[4 * k + 3] = t.w;
    }

    __shared__ float xs[16 * DD];
    __shared__ float u_lds[16];
    xs[tid]       = x[(size_t)r0 * DD + tid];
    xs[tid + 256] = x[(size_t)r0 * DD + tid + 256];
    if (tid < 16) u_lds[tid] = u[r0 + tid];
    __syncthreads();

    const float vj = v[j];
#pragma unroll 4
    for (int ii = 0; ii < 16; ++ii) {
        float acc = 0.0f;
#pragma unroll
        for (int k = 0; k < DD; ++k) {
            float d = xs[ii * DD + k] - yv[k];
            acc = fmaf(d, d, acc);
        }
        out[(size_t)(r0 + ii) * MM + j] = u_lds[ii] * __expf(-acc * INV_REG) * vj;
    }
}

extern "C" void kernel_launch(void* const* d_in, const int* in_sizes, int n_in,
                              void* d_out, int out_size, void* d_ws, size_t ws_size,
                              hipStream_t stream) {
    const float* x = (const float*)d_in[0];
    const float* y = (const float*)d_in[1];
    __half*   Kh   = (__half*)d_ws;                    // 32 MB
    __half*   KTh  = Kh + (size_t)NN * MM;             // 32 MB
    float*    u32  = (float*)(KTh + (size_t)NN * MM);  // 16 KB
    float*    v32  = u32 + NN;                         // 16 KB
    unsigned* mbu  = (unsigned*)(v32 + MM);            // 16 KB u row-mailbox
    unsigned* mbv  = mbu + NN;                         // 16 KB v row-mailbox
    float*    out  = (float*)d_out;

    compute_K_half<<<dim3(16, 256, 2), 256, 0, stream>>>(x, y, Kh, KTh, mbu, mbv);

    // Plain launch: 256 blocks (one per CU's worth of 16 waves); 4096 waves
    // always co-resident regardless of placement (device cap 8192).
    sinkhorn_persist<<<256, 1024, 0, stream>>>(Kh, KTh, u32, v32, mbu, mbv);

    epilogue<<<dim3(MM / 256, NN / 16), 256, 0, stream>>>(x, y, u32, v32, out);
}